// Round 3
// baseline (1105.152 us; speedup 1.0000x reference)
//
#include <hip/hip_runtime.h>
#include <math.h>

#define N_NODES 50000
#define N_EDGES 400000
#define DIM 512
#define NLAYER 3
#define INNER 2048
#define BN_EPS 1e-5f
#define MPAD 50048   // N_NODES rounded up to BM multiple (slack rows for global_load_lds)

typedef unsigned short u16;
typedef unsigned int u32;

typedef __attribute__((ext_vector_type(8))) short bf16x8;
typedef __attribute__((ext_vector_type(4))) float f32x4;

__device__ __forceinline__ u16 f2bf(float f) {
  union { float f; u32 u; } v; v.f = f;
  u32 u = v.u;
  u32 r = (u + 0x7FFFu + ((u >> 16) & 1u)) >> 16;  // RNE
  return (u16)r;
}
__device__ __forceinline__ float bf2f(u16 h) {
  union { u32 u; float f; } v; v.u = ((u32)h) << 16; return v.f;
}

#define GLOAD_LDS16(g, l)                                                       \
  __builtin_amdgcn_global_load_lds(                                             \
      (const __attribute__((address_space(1))) u32*)(g),                        \
      (__attribute__((address_space(3))) u32*)(l), 16, 0, 0)

// ---------------- graph prep ----------------

__global__ void k_deg(const int* __restrict__ ei, int* __restrict__ deg) {
  int e = blockIdx.x * blockDim.x + threadIdx.x;
  if (e < N_EDGES) atomicAdd(&deg[ei[N_EDGES + e]], 1);
}

__global__ void k_dinv(const int* __restrict__ deg, float* __restrict__ dinv) {
  int i = blockIdx.x * blockDim.x + threadIdx.x;
  if (i < N_NODES) dinv[i] = rsqrtf((float)(deg[i] + 1));
}

__global__ __launch_bounds__(1024) void k_scan(const int* __restrict__ deg,
                                               int* __restrict__ offs, int n) {
  __shared__ int wsum[16];
  __shared__ int carry;
  int tid = threadIdx.x;
  int lane = tid & 63, wv = tid >> 6;
  if (tid == 0) carry = 0;
  __syncthreads();
  for (int base = 0; base < n; base += 1024) {
    int i = base + tid;
    int v = (i < n) ? deg[i] : 0;
    int x = v;
#pragma unroll
    for (int d = 1; d < 64; d <<= 1) {
      int y = __shfl_up(x, d, 64);
      if (lane >= d) x += y;
    }
    if (lane == 63) wsum[wv] = x;
    __syncthreads();
    if (wv == 0) {
      int w = (lane < 16) ? wsum[lane] : 0;
#pragma unroll
      for (int d = 1; d < 16; d <<= 1) {
        int y = __shfl_up(w, d, 64);
        if (lane >= d) w += y;
      }
      if (lane < 16) wsum[lane] = w;
    }
    __syncthreads();
    int prev = carry + (wv ? wsum[wv - 1] : 0);
    if (i < n) offs[i] = prev + x - v;
    int total = wsum[15];
    __syncthreads();
    if (tid == 0) carry += total;
    __syncthreads();
  }
  if (tid == 0) offs[n] = carry;
}

__global__ void k_fill(const int* __restrict__ ei, const int* __restrict__ offs,
                       int* __restrict__ cursor, const float* __restrict__ dinv,
                       int* __restrict__ csr_src, float* __restrict__ csr_norm) {
  int e = blockIdx.x * blockDim.x + threadIdx.x;
  if (e >= N_EDGES) return;
  int s = ei[e];
  int d = ei[N_EDGES + e];
  int p = atomicAdd(&cursor[d], 1);
  int idx = offs[d] + p;
  csr_src[idx] = s;
  csr_norm[idx] = dinv[s] * dinv[d];
}

// fp32 -> bf16 elementwise (4 elems/thread)
__global__ void k_convert(const float* __restrict__ src, u16* __restrict__ dst, int n4) {
  int i = blockIdx.x * blockDim.x + threadIdx.x;
  if (i >= n4) return;
  float4 v = ((const float4*)src)[i];
  uint2 o;
  o.x = (u32)f2bf(v.x) | ((u32)f2bf(v.y) << 16);
  o.y = (u32)f2bf(v.z) | ((u32)f2bf(v.w) << 16);
  ((uint2*)dst)[i] = o;
}

// W [K,512] fp32 -> WT [512,K] bf16, optional per-k scale
__global__ void k_transpose_scale(const float* __restrict__ W, const float* __restrict__ scale,
                                  u16* __restrict__ WT, int K) {
  int t = blockIdx.x * blockDim.x + threadIdx.x;
  if (t >= K * DIM) return;
  int k = t >> 9;
  int j = t & 511;
  float v = W[t];
  if (scale) v *= scale[k];
  WT[(size_t)j * K + k] = f2bf(v);
}

// ---------------- GEMM: C[M,512] = A[M,K] @ Bt[512,K]^T, bf16 in
// m97-style: unpadded LDS, global_load_lds width-16 staging.
// XCD swizzle: the 4 n-blocks of one m-panel get flat ids differing by 8
// -> same XCD under round-robin dispatch -> A panel shared in that L2.
#define BM 128
#define BN 128
#define BK 32

__global__ __launch_bounds__(256) void gemm_bt(
    const u16* __restrict__ A0, const u16* __restrict__ A1,
    const u16* __restrict__ A2, const u16* __restrict__ A3,
    const u16* __restrict__ Bt, const float* __restrict__ bias,
    float* __restrict__ Cf, u16* __restrict__ Cb, int M, int K) {
  __shared__ __align__(16) u16 As[BM * BK];
  __shared__ __align__(16) u16 Bs[BN * BK];
  int tid = threadIdx.x;

  // swizzle: flat dispatch id -> (mb, nb), same-panel blocks 8 apart
  int Mblocks = gridDim.y;
  int flat = blockIdx.y * gridDim.x + blockIdx.x;
  int g = flat >> 5;          // 32-block group = 8 m-panels x 4 n
  int r = flat & 31;
  int P = Mblocks - (g << 3); // panels in this group
  P = (P > 8) ? 8 : P;
  int mb = (g << 3) + r % P;
  int nb = r / P;
  int m0 = mb * BM;
  int n0 = nb * BN;

  int wave = tid >> 6, lane = tid & 63;
  int wm = (wave & 1) * 64, wn = (wave >> 1) * 64;
  int lr = lane & 15;  // row within 16
  int lq = lane >> 4;  // quad

  int ric = lane >> 2;       // row in 16-row chunk
  int seg = (lane & 3) * 8;  // 8 u16 = 16B segment within 64B row

  f32x4 acc[4][4];
#pragma unroll
  for (int i = 0; i < 4; i++)
#pragma unroll
    for (int j = 0; j < 4; j++) acc[i][j] = (f32x4){0.f, 0.f, 0.f, 0.f};

  for (int k0 = 0; k0 < K; k0 += BK) {
    int b = k0 >> 9;
    int kcol = k0 & 511;
    const u16* Abase = (b == 0) ? A0 : (b == 1) ? A1 : (b == 2) ? A2 : A3;
#pragma unroll
    for (int c = 0; c < 2; c++) {
      int chunk = wave * 2 + c;
      int arow = chunk * 16 + ric;
      GLOAD_LDS16(Abase + (size_t)(m0 + arow) * DIM + kcol + seg, &As[chunk * 512]);
      GLOAD_LDS16(Bt + (size_t)(n0 + arow) * K + k0 + seg, &Bs[chunk * 512]);
    }
    __syncthreads();
    bf16x8 af[4], bfr[4];
#pragma unroll
    for (int i = 0; i < 4; i++)
      af[i] = *(const bf16x8*)(&As[(wm + i * 16 + lr) * BK + lq * 8]);
#pragma unroll
    for (int j = 0; j < 4; j++)
      bfr[j] = *(const bf16x8*)(&Bs[(wn + j * 16 + lr) * BK + lq * 8]);
#pragma unroll
    for (int i = 0; i < 4; i++)
#pragma unroll
      for (int j = 0; j < 4; j++)
        acc[i][j] = __builtin_amdgcn_mfma_f32_16x16x32_bf16(af[i], bfr[j], acc[i][j], 0, 0, 0);
    __syncthreads();
  }
  // epilogue: D[row][col], col = lane&15, row = quad*4 + reg
#pragma unroll
  for (int i = 0; i < 4; i++) {
    int row_b = m0 + wm + i * 16 + lq * 4;
#pragma unroll
    for (int j = 0; j < 4; j++) {
      int col = n0 + wn + j * 16 + lr;
      float bv = bias ? bias[col] : 0.f;
#pragma unroll
      for (int r2 = 0; r2 < 4; r2++) {
        int row = row_b + r2;
        if (row < M) {
          if (Cf) Cf[(size_t)row * DIM + col] = acc[i][j][r2] + bv;
          else    Cb[(size_t)row * DIM + col] = f2bf(acc[i][j][r2]);
        }
      }
    }
  }
}

// ---------------- aggregation: one wave per node, 16B/lane, 4-deep edge pipeline
__device__ __forceinline__ void accum8(float* a, uint4 h, float w) {
  a[0] += w * bf2f((u16)(h.x & 0xffffu));
  a[1] += w * bf2f((u16)(h.x >> 16));
  a[2] += w * bf2f((u16)(h.y & 0xffffu));
  a[3] += w * bf2f((u16)(h.y >> 16));
  a[4] += w * bf2f((u16)(h.z & 0xffffu));
  a[5] += w * bf2f((u16)(h.z >> 16));
  a[6] += w * bf2f((u16)(h.w & 0xffffu));
  a[7] += w * bf2f((u16)(h.w >> 16));
}

__global__ __launch_bounds__(256) void k_aggregate(
    const u16* __restrict__ hp, const int* __restrict__ offs,
    const int* __restrict__ csr_src, const float* __restrict__ csr_norm,
    const float* __restrict__ dinv, const float* __restrict__ b,
    u16* __restrict__ hb_out) {
  int v = blockIdx.x * 4 + (threadIdx.x >> 6);
  if (v >= N_NODES) return;
  int lane = threadIdx.x & 63;
  int c8 = lane * 8;  // 8 bf16 = 16 B per lane; wave covers the full 1KB row
  float acc[8];
#pragma unroll
  for (int i = 0; i < 8; i++) acc[i] = 0.f;

  int e0 = offs[v], e1 = offs[v + 1];
  int e = e0;
  for (; e + 4 <= e1; e += 4) {
    int s0 = csr_src[e], s1 = csr_src[e + 1], s2 = csr_src[e + 2], s3 = csr_src[e + 3];
    float w0 = csr_norm[e], w1 = csr_norm[e + 1], w2 = csr_norm[e + 2], w3 = csr_norm[e + 3];
    uint4 h0 = *(const uint4*)(hp + (size_t)s0 * DIM + c8);
    uint4 h1 = *(const uint4*)(hp + (size_t)s1 * DIM + c8);
    uint4 h2 = *(const uint4*)(hp + (size_t)s2 * DIM + c8);
    uint4 h3 = *(const uint4*)(hp + (size_t)s3 * DIM + c8);
    accum8(acc, h0, w0);
    accum8(acc, h1, w1);
    accum8(acc, h2, w2);
    accum8(acc, h3, w3);
  }
  for (; e < e1; e++) {
    int s = csr_src[e];
    float w = csr_norm[e];
    uint4 hv = *(const uint4*)(hp + (size_t)s * DIM + c8);
    accum8(acc, hv, w);
  }
  // self loop
  float di = dinv[v];
  uint4 hv = *(const uint4*)(hp + (size_t)v * DIM + c8);
  accum8(acc, hv, di * di);
  // bias + exact GELU + pack
  const float4* bb = (const float4*)(b + c8);
  float4 b0 = bb[0], b1 = bb[1];
  acc[0] += b0.x; acc[1] += b0.y; acc[2] += b0.z; acc[3] += b0.w;
  acc[4] += b1.x; acc[5] += b1.y; acc[6] += b1.z; acc[7] += b1.w;
#pragma unroll
  for (int i = 0; i < 8; i++)
    acc[i] = 0.5f * acc[i] * (1.f + erff(acc[i] * 0.70710678118654752f));
  uint4 o;
  o.x = (u32)f2bf(acc[0]) | ((u32)f2bf(acc[1]) << 16);
  o.y = (u32)f2bf(acc[2]) | ((u32)f2bf(acc[3]) << 16);
  o.z = (u32)f2bf(acc[4]) | ((u32)f2bf(acc[5]) << 16);
  o.w = (u32)f2bf(acc[6]) | ((u32)f2bf(acc[7]) << 16);
  *(uint4*)(hb_out + (size_t)v * DIM + c8) = o;
}

// ---------------- BN stats ----------------
__global__ void k_bn_stats(const u16* __restrict__ b0, const u16* __restrict__ b1,
                           const u16* __restrict__ b2, const u16* __restrict__ b3,
                           float* __restrict__ sums, float* __restrict__ sumsq,
                           int rows_per) {
  const u16* buf = (blockIdx.x == 0) ? b0 : (blockIdx.x == 1) ? b1 : (blockIdx.x == 2) ? b2 : b3;
  int c = threadIdx.x * 2;
  int col = blockIdx.x * DIM + c;
  int r0 = blockIdx.y * rows_per;
  int r1 = min(N_NODES, r0 + rows_per);
  float s0 = 0.f, ss0 = 0.f, s1 = 0.f, ss1 = 0.f;
  for (int r = r0; r < r1; r++) {
    u32 u = *(const u32*)(buf + (size_t)r * DIM + c);
    float x0 = bf2f((u16)(u & 0xffffu));
    float x1 = bf2f((u16)(u >> 16));
    s0 += x0; ss0 += x0 * x0;
    s1 += x1; ss1 += x1 * x1;
  }
  atomicAdd(&sums[col], s0);
  atomicAdd(&sumsq[col], ss0);
  atomicAdd(&sums[col + 1], s1);
  atomicAdd(&sumsq[col + 1], ss1);
}

__global__ void k_bn_finalize(const float* __restrict__ sums, const float* __restrict__ sumsq,
                              const float* __restrict__ gamma, const float* __restrict__ beta,
                              float* __restrict__ scale, float* __restrict__ shift) {
  int c = blockIdx.x * blockDim.x + threadIdx.x;
  if (c >= INNER) return;
  float mean = sums[c] / (float)N_NODES;
  float var = sumsq[c] / (float)N_NODES - mean * mean;
  float rstd = rsqrtf(var + BN_EPS);
  float sc = gamma[c] * rstd;
  scale[c] = sc;
  shift[c] = beta[c] - mean * sc;
}

__global__ void k_fold_bias(const float* __restrict__ outW, const float* __restrict__ shift,
                            const float* __restrict__ outb, float* __restrict__ biasp) {
  int j = blockIdx.x * blockDim.x + threadIdx.x;
  if (j >= DIM) return;
  float s = 0.f;
  for (int k = 0; k < INNER; k++) s += shift[k] * outW[(size_t)k * DIM + j];
  biasp[j] = s + outb[j];
}

// ---------------- launch ----------------
extern "C" void kernel_launch(void* const* d_in, const int* in_sizes, int n_in,
                              void* d_out, int out_size, void* d_ws, size_t ws_size,
                              hipStream_t stream) {
  (void)in_sizes; (void)n_in; (void)out_size; (void)ws_size;
  const float* x     = (const float*)d_in[0];
  const int*   ei    = (const int*)d_in[1];
  const float* Ws    = (const float*)d_in[2];
  const float* bs    = (const float*)d_in[3];
  const float* gamma = (const float*)d_in[4];
  const float* beta  = (const float*)d_in[5];
  const float* outW  = (const float*)d_in[6];
  const float* outb  = (const float*)d_in[7];
  float* out = (float*)d_out;
  u16*   hp  = (u16*)d_out;  // bf16 h scratch lives in d_out until the final GEMM

  char* ws = (char*)d_ws;
  size_t off = 0;
  auto alloc = [&](size_t bytes) -> void* {
    void* p = ws + off;
    off = (off + bytes + 255) & ~(size_t)255;
    return p;
  };
  // zeroed region first (single memset)
  int*   deg    = (int*)alloc(N_NODES * 4);
  int*   cursor = (int*)alloc(N_NODES * 4);
  float* sums   = (float*)alloc(INNER * 4);
  float* sumsq  = (float*)alloc(INNER * 4);
  size_t zero_bytes = off;
  float* dinv     = (float*)alloc(N_NODES * 4);
  int*   offs     = (int*)alloc((N_NODES + 1) * 4);
  int*   csr_src  = (int*)alloc(N_EDGES * 4);
  float* csr_norm = (float*)alloc(N_EDGES * 4);
  u16*   xb  = (u16*)alloc((size_t)MPAD * DIM * 2);  // MPAD rows: gemm staging slack
  u16*   hb1 = (u16*)alloc((size_t)MPAD * DIM * 2);
  u16*   hb2 = (u16*)alloc((size_t)MPAD * DIM * 2);
  u16*   hb3 = (u16*)alloc((size_t)MPAD * DIM * 2);
  u16*   WbT = (u16*)alloc((size_t)DIM * DIM * 2);
  u16*   WpT = (u16*)alloc((size_t)INNER * DIM * 2);
  float* scale = (float*)alloc(INNER * 4);
  float* shift = (float*)alloc(INNER * 4);
  float* biasp = (float*)alloc(DIM * 4);

  hipMemsetAsync(d_ws, 0, zero_bytes, stream);
  k_deg<<<(N_EDGES + 255) / 256, 256, 0, stream>>>(ei, deg);
  k_dinv<<<(N_NODES + 255) / 256, 256, 0, stream>>>(deg, dinv);
  k_scan<<<1, 1024, 0, stream>>>(deg, offs, N_NODES);
  k_fill<<<(N_EDGES + 255) / 256, 256, 0, stream>>>(ei, offs, cursor, dinv, csr_src, csr_norm);
  k_convert<<<((N_NODES * DIM / 4) + 255) / 256, 256, 0, stream>>>(x, xb, N_NODES * DIM / 4);

  u16* Abufs[4] = {xb, hb1, hb2, hb3};
  dim3 ggrid(DIM / BN, (N_NODES + BM - 1) / BM);
  for (int l = 0; l < NLAYER; l++) {
    k_transpose_scale<<<(DIM * DIM + 255) / 256, 256, 0, stream>>>(
        Ws + (size_t)l * DIM * DIM, nullptr, WbT, DIM);
    const u16* Al = Abufs[l];
    gemm_bt<<<ggrid, 256, 0, stream>>>(Al, Al, Al, Al, WbT, nullptr,
                                       nullptr, hp, N_NODES, DIM);
    k_aggregate<<<(N_NODES + 3) / 4, 256, 0, stream>>>(hp, offs, csr_src, csr_norm, dinv,
                                                       bs + (size_t)l * DIM, Abufs[l + 1]);
  }
  k_bn_stats<<<dim3(4, 125), 256, 0, stream>>>(xb, hb1, hb2, hb3, sums, sumsq, 400);
  k_bn_finalize<<<INNER / 256, 256, 0, stream>>>(sums, sumsq, gamma, beta, scale, shift);
  k_transpose_scale<<<(INNER * DIM + 255) / 256, 256, 0, stream>>>(outW, scale, WpT, INNER);
  k_fold_bias<<<2, 256, 0, stream>>>(outW, shift, outb, biasp);
  gemm_bt<<<ggrid, 256, 0, stream>>>(xb, hb1, hb2, hb3, WpT, biasp,
                                     out, nullptr, N_NODES, INNER);
}

// Round 4
// 925.300 us; speedup vs baseline: 1.1944x; 1.1944x over previous
//
#include <hip/hip_runtime.h>
#include <math.h>

#define N_NODES 50000
#define N_EDGES 400000
#define DIM 512
#define NLAYER 3
#define INNER 2048
#define BN_EPS 1e-5f
#define MPAD 50048   // N_NODES rounded up to BM multiple (slack rows for global_load_lds)

typedef unsigned short u16;
typedef unsigned int u32;

typedef __attribute__((ext_vector_type(8))) short bf16x8;
typedef __attribute__((ext_vector_type(4))) float f32x4;

__device__ __forceinline__ u16 f2bf(float f) {
  union { float f; u32 u; } v; v.f = f;
  u32 u = v.u;
  u32 r = (u + 0x7FFFu + ((u >> 16) & 1u)) >> 16;  // RNE
  return (u16)r;
}
__device__ __forceinline__ float bf2f(u16 h) {
  union { u32 u; float f; } v; v.u = ((u32)h) << 16; return v.f;
}

#define GLOAD_LDS16(g, l)                                                       \
  __builtin_amdgcn_global_load_lds(                                             \
      (const __attribute__((address_space(1))) u32*)(g),                        \
      (__attribute__((address_space(3))) u32*)(l), 16, 0, 0)

// ---------------- graph prep ----------------

__global__ void k_deg(const int* __restrict__ ei, int* __restrict__ deg) {
  int e = blockIdx.x * blockDim.x + threadIdx.x;
  if (e < N_EDGES) atomicAdd(&deg[ei[N_EDGES + e]], 1);
}

__global__ void k_dinv(const int* __restrict__ deg, float* __restrict__ dinv) {
  int i = blockIdx.x * blockDim.x + threadIdx.x;
  if (i < N_NODES) dinv[i] = rsqrtf((float)(deg[i] + 1));
}

// parallel 3-phase scan (was: single-block serial, ~49 barriered iterations)
__global__ __launch_bounds__(1024) void k_scan1(const int* __restrict__ deg,
                                                int* __restrict__ bsum, int n) {
  __shared__ int wsum[16];
  int tid = threadIdx.x;
  int lane = tid & 63, wv = tid >> 6;
  int i = blockIdx.x * 1024 + tid;
  int x = (i < n) ? deg[i] : 0;
#pragma unroll
  for (int d = 1; d < 64; d <<= 1) x += __shfl_xor(x, d, 64);
  if (lane == 0) wsum[wv] = x;
  __syncthreads();
  if (tid == 0) {
    int s = 0;
#pragma unroll
    for (int k = 0; k < 16; k++) s += wsum[k];
    bsum[blockIdx.x] = s;
  }
}

__global__ void k_scan2(int* __restrict__ bsum, int* __restrict__ offs, int nb) {
  int lane = threadIdx.x;  // 64 threads, nb <= 64
  int v = (lane < nb) ? bsum[lane] : 0;
  int x = v;
#pragma unroll
  for (int d = 1; d < 64; d <<= 1) {
    int y = __shfl_up(x, d, 64);
    if (lane >= d) x += y;
  }
  if (lane < nb) bsum[lane] = x - v;  // exclusive base per block
  if (lane == nb - 1) offs[N_NODES] = x;  // grand total
}

__global__ __launch_bounds__(1024) void k_scan3(const int* __restrict__ deg,
                                                const int* __restrict__ bsum,
                                                int* __restrict__ offs, int n) {
  __shared__ int wsum[16];
  int tid = threadIdx.x;
  int lane = tid & 63, wv = tid >> 6;
  int i = blockIdx.x * 1024 + tid;
  int v = (i < n) ? deg[i] : 0;
  int x = v;
#pragma unroll
  for (int d = 1; d < 64; d <<= 1) {
    int y = __shfl_up(x, d, 64);
    if (lane >= d) x += y;
  }
  if (lane == 63) wsum[wv] = x;
  __syncthreads();
  if (wv == 0) {
    int w = (lane < 16) ? wsum[lane] : 0;
#pragma unroll
    for (int d = 1; d < 16; d <<= 1) {
      int y = __shfl_up(w, d, 64);
      if (lane >= d) w += y;
    }
    if (lane < 16) wsum[lane] = w;
  }
  __syncthreads();
  if (i < n) offs[i] = bsum[blockIdx.x] + (wv ? wsum[wv - 1] : 0) + x - v;
}

__global__ void k_fill(const int* __restrict__ ei, const int* __restrict__ offs,
                       int* __restrict__ cursor, const float* __restrict__ dinv,
                       int* __restrict__ csr_src, float* __restrict__ csr_norm) {
  int e = blockIdx.x * blockDim.x + threadIdx.x;
  if (e >= N_EDGES) return;
  int s = ei[e];
  int d = ei[N_EDGES + e];
  int p = atomicAdd(&cursor[d], 1);
  int idx = offs[d] + p;
  csr_src[idx] = s;
  csr_norm[idx] = dinv[s] * dinv[d];
}

// fp32 x -> bf16 into xcat column slice 0 (row stride INNER)
__global__ void k_convert(const float* __restrict__ src, u16* __restrict__ xcat, int n4) {
  int i = blockIdx.x * blockDim.x + threadIdx.x;
  if (i >= n4) return;
  float4 v = ((const float4*)src)[i];
  uint2 o;
  o.x = (u32)f2bf(v.x) | ((u32)f2bf(v.y) << 16);
  o.y = (u32)f2bf(v.z) | ((u32)f2bf(v.w) << 16);
  int row = i >> 7;            // DIM/4 = 128 chunks per row
  int c4 = (i & 127) * 4;
  *(uint2*)(xcat + (size_t)row * INNER + c4) = o;
}

// LDS-tiled transpose: W [K,512] fp32 -> WT [512,K] bf16, optional per-k scale.
// Coalesced reads AND writes (old version scattered 2B writes, 4KB apart).
__global__ __launch_bounds__(256) void k_transpose_tiled(
    const float* __restrict__ W, const float* __restrict__ scale,
    u16* __restrict__ WT, int K) {
  __shared__ float tile[32][33];
  int k0 = blockIdx.x * 32, j0 = blockIdx.y * 32;
  int c = threadIdx.x & 31, r8 = threadIdx.x >> 5;  // 8 rows per pass
#pragma unroll
  for (int rr = 0; rr < 4; rr++) {
    int row = rr * 8 + r8;
    float v = W[(size_t)(k0 + row) * DIM + j0 + c];
    if (scale) v *= scale[k0 + row];
    tile[row][c] = v;
  }
  __syncthreads();
#pragma unroll
  for (int rr = 0; rr < 4; rr++) {
    int row = rr * 8 + r8;
    WT[(size_t)(j0 + row) * K + k0 + c] = f2bf(tile[c][row]);
  }
}

// ---------------- GEMM: C[M,512] = A[M,K](lda) @ Bt[512,K]^T, bf16 in
// m97-style staging via global_load_lds w=16; loop-carried pointers (no per-iter
// address rebuild); XCD swizzle keeps the 4 n-blocks of an m-panel on one XCD.
#define BM 128
#define BN 128
#define BK 32

__global__ __launch_bounds__(256) void gemm_bt(
    const u16* __restrict__ A, int lda,
    const u16* __restrict__ Bt, const float* __restrict__ bias,
    float* __restrict__ Cf, u16* __restrict__ Cb, int M, int K) {
  __shared__ __align__(16) u16 As[BM * BK];
  __shared__ __align__(16) u16 Bs[BN * BK];
  int tid = threadIdx.x;

  int Mblocks = gridDim.y;
  int flat = blockIdx.y * gridDim.x + blockIdx.x;
  int g = flat >> 5;
  int r = flat & 31;
  int P = Mblocks - (g << 3);
  P = (P > 8) ? 8 : P;
  int mb = (g << 3) + r % P;
  int nb = r / P;
  int m0 = mb * BM;
  int n0 = nb * BN;

  int wave = tid >> 6, lane = tid & 63;
  int wm = (wave & 1) * 64, wn = (wave >> 1) * 64;
  int lr = lane & 15;
  int lq = lane >> 4;
  int ric = lane >> 2;       // row in 16-row chunk
  int seg = (lane & 3) * 8;  // 16B segment

  // loop-carried staging pointers: wave w stages chunks 2w,2w+1 of A and B
  const u16* ap0 = A + (size_t)(m0 + wave * 32 + ric) * lda + seg;
  const u16* ap1 = ap0 + (size_t)16 * lda;
  const u16* bp0 = Bt + (size_t)(n0 + wave * 32 + ric) * K + seg;
  const u16* bp1 = bp0 + (size_t)16 * K;
  u16* asl0 = &As[(wave * 2) * 512];
  u16* asl1 = asl0 + 512;
  u16* bsl0 = &Bs[(wave * 2) * 512];
  u16* bsl1 = bsl0 + 512;

  f32x4 acc[4][4];
#pragma unroll
  for (int i = 0; i < 4; i++)
#pragma unroll
    for (int j = 0; j < 4; j++) acc[i][j] = (f32x4){0.f, 0.f, 0.f, 0.f};

  for (int k0 = 0; k0 < K; k0 += BK) {
    GLOAD_LDS16(ap0, asl0);
    GLOAD_LDS16(ap1, asl1);
    GLOAD_LDS16(bp0, bsl0);
    GLOAD_LDS16(bp1, bsl1);
    ap0 += BK; ap1 += BK; bp0 += BK; bp1 += BK;
    __syncthreads();
    bf16x8 af[4], bfr[4];
#pragma unroll
    for (int i = 0; i < 4; i++)
      af[i] = *(const bf16x8*)(&As[(wm + i * 16 + lr) * BK + lq * 8]);
#pragma unroll
    for (int j = 0; j < 4; j++)
      bfr[j] = *(const bf16x8*)(&Bs[(wn + j * 16 + lr) * BK + lq * 8]);
#pragma unroll
    for (int i = 0; i < 4; i++)
#pragma unroll
      for (int j = 0; j < 4; j++)
        acc[i][j] = __builtin_amdgcn_mfma_f32_16x16x32_bf16(af[i], bfr[j], acc[i][j], 0, 0, 0);
    __syncthreads();
  }
  // epilogue: D[row][col], col = lane&15, row = quad*4 + reg
#pragma unroll
  for (int i = 0; i < 4; i++) {
    int row_b = m0 + wm + i * 16 + lq * 4;
#pragma unroll
    for (int j = 0; j < 4; j++) {
      int col = n0 + wn + j * 16 + lr;
      if (Cf) {
        float bv = bias ? bias[col] : 0.f;
#pragma unroll
        for (int r2 = 0; r2 < 4; r2++) {
          int row = row_b + r2;
          if (row < M) Cf[(size_t)row * DIM + col] = acc[i][j][r2] + bv;
        }
      } else {
        // bf16 scratch has MPAD rows: no bound check needed
#pragma unroll
        for (int r2 = 0; r2 < 4; r2++)
          Cb[(size_t)(row_b + r2) * DIM + col] = f2bf(acc[i][j][r2]);
      }
    }
  }
}

// ---------------- aggregation: one wave per node, 16B/lane, 4-deep edge pipeline
__device__ __forceinline__ void accum8(float* a, uint4 h, float w) {
  a[0] += w * bf2f((u16)(h.x & 0xffffu));
  a[1] += w * bf2f((u16)(h.x >> 16));
  a[2] += w * bf2f((u16)(h.y & 0xffffu));
  a[3] += w * bf2f((u16)(h.y >> 16));
  a[4] += w * bf2f((u16)(h.z & 0xffffu));
  a[5] += w * bf2f((u16)(h.z >> 16));
  a[6] += w * bf2f((u16)(h.w & 0xffffu));
  a[7] += w * bf2f((u16)(h.w >> 16));
}

// reads hp [*,DIM] dense; writes GELU(agg)+bias into xcat column slice (stride INNER)
__global__ __launch_bounds__(256) void k_aggregate(
    const u16* __restrict__ hp, const int* __restrict__ offs,
    const int* __restrict__ csr_src, const float* __restrict__ csr_norm,
    const float* __restrict__ dinv, const float* __restrict__ b,
    u16* __restrict__ out_slice) {
  int v = blockIdx.x * 4 + (threadIdx.x >> 6);
  if (v >= N_NODES) return;
  int lane = threadIdx.x & 63;
  int c8 = lane * 8;  // 8 bf16 = 16 B per lane; wave covers the full 1KB row
  float acc[8];
#pragma unroll
  for (int i = 0; i < 8; i++) acc[i] = 0.f;

  int e0 = offs[v], e1 = offs[v + 1];
  int e = e0;
  for (; e + 4 <= e1; e += 4) {
    int s0 = csr_src[e], s1 = csr_src[e + 1], s2 = csr_src[e + 2], s3 = csr_src[e + 3];
    float w0 = csr_norm[e], w1 = csr_norm[e + 1], w2 = csr_norm[e + 2], w3 = csr_norm[e + 3];
    uint4 h0 = *(const uint4*)(hp + (size_t)s0 * DIM + c8);
    uint4 h1 = *(const uint4*)(hp + (size_t)s1 * DIM + c8);
    uint4 h2 = *(const uint4*)(hp + (size_t)s2 * DIM + c8);
    uint4 h3 = *(const uint4*)(hp + (size_t)s3 * DIM + c8);
    accum8(acc, h0, w0);
    accum8(acc, h1, w1);
    accum8(acc, h2, w2);
    accum8(acc, h3, w3);
  }
  for (; e < e1; e++) {
    int s = csr_src[e];
    float w = csr_norm[e];
    uint4 hv = *(const uint4*)(hp + (size_t)s * DIM + c8);
    accum8(acc, hv, w);
  }
  float di = dinv[v];
  uint4 hv = *(const uint4*)(hp + (size_t)v * DIM + c8);
  accum8(acc, hv, di * di);
  const float4* bb = (const float4*)(b + c8);
  float4 b0 = bb[0], b1 = bb[1];
  acc[0] += b0.x; acc[1] += b0.y; acc[2] += b0.z; acc[3] += b0.w;
  acc[4] += b1.x; acc[5] += b1.y; acc[6] += b1.z; acc[7] += b1.w;
#pragma unroll
  for (int i = 0; i < 8; i++)
    acc[i] = 0.5f * acc[i] * (1.f + erff(acc[i] * 0.70710678118654752f));
  uint4 o;
  o.x = (u32)f2bf(acc[0]) | ((u32)f2bf(acc[1]) << 16);
  o.y = (u32)f2bf(acc[2]) | ((u32)f2bf(acc[3]) << 16);
  o.z = (u32)f2bf(acc[4]) | ((u32)f2bf(acc[5]) << 16);
  o.w = (u32)f2bf(acc[6]) | ((u32)f2bf(acc[7]) << 16);
  *(uint4*)(out_slice + (size_t)v * INNER + c8) = o;
}

// ---------------- BN stats over xcat [N_NODES, INNER] ----------------
__global__ void k_bn_stats(const u16* __restrict__ xcat,
                           float* __restrict__ sums, float* __restrict__ sumsq,
                           int rows_per) {
  int c = blockIdx.x * 512 + threadIdx.x * 2;  // column pair
  int r0 = blockIdx.y * rows_per;
  int r1 = min(N_NODES, r0 + rows_per);
  float s0 = 0.f, ss0 = 0.f, s1 = 0.f, ss1 = 0.f;
  for (int r = r0; r < r1; r++) {
    u32 u = *(const u32*)(xcat + (size_t)r * INNER + c);
    float x0 = bf2f((u16)(u & 0xffffu));
    float x1 = bf2f((u16)(u >> 16));
    s0 += x0; ss0 += x0 * x0;
    s1 += x1; ss1 += x1 * x1;
  }
  atomicAdd(&sums[c], s0);
  atomicAdd(&sumsq[c], ss0);
  atomicAdd(&sums[c + 1], s1);
  atomicAdd(&sumsq[c + 1], ss1);
}

__global__ void k_bn_finalize(const float* __restrict__ sums, const float* __restrict__ sumsq,
                              const float* __restrict__ gamma, const float* __restrict__ beta,
                              float* __restrict__ scale, float* __restrict__ shift) {
  int c = blockIdx.x * blockDim.x + threadIdx.x;
  if (c >= INNER) return;
  float mean = sums[c] / (float)N_NODES;
  float var = sumsq[c] / (float)N_NODES - mean * mean;
  float rstd = rsqrtf(var + BN_EPS);
  float sc = gamma[c] * rstd;
  scale[c] = sc;
  shift[c] = beta[c] - mean * sc;
}

// biasp (zero-initialized) += sum_k shift[k]*outW[k][:]; block 0 also adds outb
__global__ __launch_bounds__(256) void k_fold_bias(
    const float* __restrict__ outW, const float* __restrict__ shift,
    const float* __restrict__ outb, float* __restrict__ biasp) {
  int r0 = blockIdx.x * 64;  // 32 blocks x 64 rows
  int c = threadIdx.x * 2;
  float s0 = 0.f, s1 = 0.f;
  for (int r = 0; r < 64; r++) {
    int row = r0 + r;
    float sh = shift[row];
    float2 w = *(const float2*)(outW + (size_t)row * DIM + c);
    s0 += sh * w.x;
    s1 += sh * w.y;
  }
  if (blockIdx.x == 0) { s0 += outb[c]; s1 += outb[c + 1]; }
  atomicAdd(&biasp[c], s0);
  atomicAdd(&biasp[c + 1], s1);
}

// ---------------- launch ----------------
extern "C" void kernel_launch(void* const* d_in, const int* in_sizes, int n_in,
                              void* d_out, int out_size, void* d_ws, size_t ws_size,
                              hipStream_t stream) {
  (void)in_sizes; (void)n_in; (void)out_size; (void)ws_size;
  const float* x     = (const float*)d_in[0];
  const int*   ei    = (const int*)d_in[1];
  const float* Ws    = (const float*)d_in[2];
  const float* bs    = (const float*)d_in[3];
  const float* gamma = (const float*)d_in[4];
  const float* beta  = (const float*)d_in[5];
  const float* outW  = (const float*)d_in[6];
  const float* outb  = (const float*)d_in[7];
  float* out = (float*)d_out;
  u16*   hp  = (u16*)d_out;  // bf16 h scratch lives in d_out until the final GEMM

  char* ws = (char*)d_ws;
  size_t off = 0;
  auto alloc = [&](size_t bytes) -> void* {
    void* p = ws + off;
    off = (off + bytes + 255) & ~(size_t)255;
    return p;
  };
  // zeroed region first (single memset)
  int*   deg    = (int*)alloc(N_NODES * 4);
  int*   cursor = (int*)alloc(N_NODES * 4);
  float* sums   = (float*)alloc(INNER * 4);
  float* sumsq  = (float*)alloc(INNER * 4);
  float* biasp  = (float*)alloc(DIM * 4);
  size_t zero_bytes = off;
  float* dinv     = (float*)alloc(N_NODES * 4);
  int*   offs     = (int*)alloc((N_NODES + 1) * 4);
  int*   bsum     = (int*)alloc(64 * 4);
  int*   csr_src  = (int*)alloc(N_EDGES * 4);
  float* csr_norm = (float*)alloc(N_EDGES * 4);
  u16*   xcat = (u16*)alloc((size_t)MPAD * INNER * 2);  // unified concat [MPAD, 2048]
  u16*   WbT  = (u16*)alloc((size_t)DIM * DIM * 2);
  u16*   WpT  = (u16*)alloc((size_t)INNER * DIM * 2);
  float* scale = (float*)alloc(INNER * 4);
  float* shift = (float*)alloc(INNER * 4);

  const int SCAN_BLOCKS = (N_NODES + 1023) / 1024;  // 49

  hipMemsetAsync(d_ws, 0, zero_bytes, stream);
  k_deg<<<(N_EDGES + 255) / 256, 256, 0, stream>>>(ei, deg);
  k_dinv<<<(N_NODES + 255) / 256, 256, 0, stream>>>(deg, dinv);
  k_scan1<<<SCAN_BLOCKS, 1024, 0, stream>>>(deg, bsum, N_NODES);
  k_scan2<<<1, 64, 0, stream>>>(bsum, offs, SCAN_BLOCKS);
  k_scan3<<<SCAN_BLOCKS, 1024, 0, stream>>>(deg, bsum, offs, N_NODES);
  k_fill<<<(N_EDGES + 255) / 256, 256, 0, stream>>>(ei, offs, cursor, dinv, csr_src, csr_norm);
  k_convert<<<((N_NODES * DIM / 4) + 255) / 256, 256, 0, stream>>>(x, xcat, N_NODES * DIM / 4);

  dim3 ggrid(DIM / BN, MPAD / BM);
  for (int l = 0; l < NLAYER; l++) {
    k_transpose_tiled<<<dim3(DIM / 32, DIM / 32), 256, 0, stream>>>(
        Ws + (size_t)l * DIM * DIM, nullptr, WbT, DIM);
    gemm_bt<<<ggrid, 256, 0, stream>>>(xcat + (size_t)l * DIM, INNER, WbT, nullptr,
                                       nullptr, hp, N_NODES, DIM);
    k_aggregate<<<(N_NODES + 3) / 4, 256, 0, stream>>>(hp, offs, csr_src, csr_norm, dinv,
                                                       bs + (size_t)l * DIM,
                                                       xcat + (size_t)(l + 1) * DIM);
  }
  k_bn_stats<<<dim3(INNER / 512, 125), 256, 0, stream>>>(xcat, sums, sumsq, 400);
  k_bn_finalize<<<INNER / 256, 256, 0, stream>>>(sums, sumsq, gamma, beta, scale, shift);
  k_transpose_tiled<<<dim3(INNER / 32, DIM / 32), 256, 0, stream>>>(outW, scale, WpT, INNER);
  k_fold_bias<<<INNER / 64, 256, 0, stream>>>(outW, shift, outb, biasp);
  gemm_bt<<<ggrid, 256, 0, stream>>>(xcat, INNER, WpT, biasp,
                                     out, nullptr, N_NODES, INNER);
}